// Round 1
// baseline (1659.261 us; speedup 1.0000x reference)
//
#include <hip/hip_runtime.h>
#include <math.h>

#define NPT 80000
#define CH 64
#define KN 27
#define NCE (NPT * CH)      // 5,120,000
#define CA 192
#define HID 12
#define EPSV 1e-5f

// ---------------------------------------------------------------------------
// Sparse conv: y[n][co] = sum_k sum_ci gather(x,nbr[n][k])[ci] * W[k][ci][co]
// Block: 64 points x 64 out-channels, 256 threads, 4x4 tile per thread.
// ---------------------------------------------------------------------------
__global__ __launch_bounds__(256) void conv_k(
    const float* __restrict__ xin, const int* __restrict__ nbr,
    const float* __restrict__ W, float* __restrict__ yout)
{
    __shared__ float xgT[CH][68];   // [ci][p], padded
    __shared__ float Wl[CH][64];    // [ci][co]
    __shared__ int   idxs[KN][64];  // [k][p]

    const int t = threadIdx.x;
    const int base = blockIdx.x * 64;

    for (int j = t; j < 64 * KN; j += 256) {
        idxs[j % KN][j / KN] = nbr[(size_t)base * KN + j];
    }

    const int p  = t & 63;      // gather point
    const int cq = t >> 6;      // channel quarter (16 ch)
    const int tr = t >> 4;      // output row group (4 rows)
    const int tc = t & 15;      // output col group (4 cols)

    float4 acc0 = {0.f,0.f,0.f,0.f}, acc1 = acc0, acc2 = acc0, acc3 = acc0;

    for (int k = 0; k < KN; ++k) {
        __syncthreads();
        // stage W[k] (64x64) -> LDS, coalesced
        const float4* Wg  = (const float4*)(W + (size_t)k * CH * 64);
        float4*       Wl4 = (float4*)&Wl[0][0];
        #pragma unroll
        for (int j = 0; j < 4; ++j) Wl4[j * 256 + t] = Wg[j * 256 + t];

        // gather one point-row quarter, write transposed
        int idx = idxs[k][p];
        float4 v0 = {0.f,0.f,0.f,0.f}, v1 = v0, v2 = v0, v3 = v0;
        if (idx >= 0) {
            const float4* xr = (const float4*)(xin + (size_t)idx * CH + cq * 16);
            v0 = xr[0]; v1 = xr[1]; v2 = xr[2]; v3 = xr[3];
        }
        const int cb = cq * 16;
        xgT[cb+ 0][p]=v0.x; xgT[cb+ 1][p]=v0.y; xgT[cb+ 2][p]=v0.z; xgT[cb+ 3][p]=v0.w;
        xgT[cb+ 4][p]=v1.x; xgT[cb+ 5][p]=v1.y; xgT[cb+ 6][p]=v1.z; xgT[cb+ 7][p]=v1.w;
        xgT[cb+ 8][p]=v2.x; xgT[cb+ 9][p]=v2.y; xgT[cb+10][p]=v2.z; xgT[cb+11][p]=v2.w;
        xgT[cb+12][p]=v3.x; xgT[cb+13][p]=v3.y; xgT[cb+14][p]=v3.z; xgT[cb+15][p]=v3.w;
        __syncthreads();

        #pragma unroll
        for (int ci = 0; ci < CH; ++ci) {
            float4 xv = *(const float4*)&xgT[ci][tr * 4];
            float4 wv = *(const float4*)&Wl[ci][tc * 4];
            acc0.x += xv.x * wv.x; acc0.y += xv.x * wv.y; acc0.z += xv.x * wv.z; acc0.w += xv.x * wv.w;
            acc1.x += xv.y * wv.x; acc1.y += xv.y * wv.y; acc1.z += xv.y * wv.z; acc1.w += xv.y * wv.w;
            acc2.x += xv.z * wv.x; acc2.y += xv.z * wv.y; acc2.z += xv.z * wv.z; acc2.w += xv.z * wv.w;
            acc3.x += xv.w * wv.x; acc3.y += xv.w * wv.y; acc3.z += xv.w * wv.z; acc3.w += xv.w * wv.w;
        }
    }

    const size_t ro = (size_t)(base + tr * 4) * CH + tc * 4;
    *(float4*)(yout + ro)          = acc0;
    *(float4*)(yout + ro + CH)     = acc1;
    *(float4*)(yout + ro + 2*CH)   = acc2;
    *(float4*)(yout + ro + 3*CH)   = acc3;
}

// ---------------------------------------------------------------------------
// BN stats: per-channel sum & sumsq via block partials + atomics
// ---------------------------------------------------------------------------
__global__ __launch_bounds__(256) void bnstats_k(const float* __restrict__ y,
    float* __restrict__ sums, float* __restrict__ ssq)
{
    const int t = threadIdx.x, c = t & 63, rg = t >> 6;
    float s = 0.f, ss = 0.f;
    for (int row = blockIdx.x * 4 + rg; row < NPT; row += gridDim.x * 4) {
        float v = y[(size_t)row * CH + c];
        s += v; ss += v * v;
    }
    __shared__ float ls[4][64], lss[4][64];
    ls[rg][c] = s; lss[rg][c] = ss;
    __syncthreads();
    if (t < 64) {
        float a = ls[0][t] + ls[1][t] + ls[2][t] + ls[3][t];
        float q = lss[0][t] + lss[1][t] + lss[2][t] + lss[3][t];
        atomicAdd(&sums[t], a);
        atomicAdd(&ssq[t], q);
    }
}

// ---------------------------------------------------------------------------
// BN apply (+optional ReLU), float4 vectorized
// ---------------------------------------------------------------------------
template<bool RELU>
__global__ __launch_bounds__(256) void bnapply_k(const float* __restrict__ y,
    const float* __restrict__ sums, const float* __restrict__ ssq,
    const float* __restrict__ g, const float* __restrict__ b,
    float* __restrict__ o)
{
    const float inv = 1.0f / (float)NPT;
    for (int i = blockIdx.x * blockDim.x + threadIdx.x; i < NCE / 4;
         i += gridDim.x * blockDim.x) {
        float4 v = ((const float4*)y)[i];
        const int c0 = (i * 4) & 63;
        float4 r;
        {
            float m = sums[c0+0]*inv; float va = ssq[c0+0]*inv - m*m;
            float sc = rsqrtf(va + EPSV) * g[c0+0];
            r.x = (v.x - m) * sc + b[c0+0];
        }
        {
            float m = sums[c0+1]*inv; float va = ssq[c0+1]*inv - m*m;
            float sc = rsqrtf(va + EPSV) * g[c0+1];
            r.y = (v.y - m) * sc + b[c0+1];
        }
        {
            float m = sums[c0+2]*inv; float va = ssq[c0+2]*inv - m*m;
            float sc = rsqrtf(va + EPSV) * g[c0+2];
            r.z = (v.z - m) * sc + b[c0+2];
        }
        {
            float m = sums[c0+3]*inv; float va = ssq[c0+3]*inv - m*m;
            float sc = rsqrtf(va + EPSV) * g[c0+3];
            r.w = (v.w - m) * sc + b[c0+3];
        }
        if (RELU) {
            r.x = fmaxf(r.x, 0.f); r.y = fmaxf(r.y, 0.f);
            r.z = fmaxf(r.z, 0.f); r.w = fmaxf(r.w, 0.f);
        }
        ((float4*)o)[i] = r;
    }
}

// ---------------------------------------------------------------------------
// Channel attention: segment sum/max over rows (B=2), monotone-uint max trick
// ---------------------------------------------------------------------------
__device__ __forceinline__ unsigned encf(float f) {
    unsigned u = __float_as_uint(f);
    return (u & 0x80000000u) ? ~u : (u | 0x80000000u);
}
__device__ __forceinline__ float decf(unsigned e) {
    return __uint_as_float((e & 0x80000000u) ? (e & 0x7fffffffu) : ~e);
}

__global__ __launch_bounds__(192) void segstat_k(const float* __restrict__ k0,
    const float* __restrict__ k1, const float* __restrict__ k2,
    const int* __restrict__ bidx, float* __restrict__ segsum,
    unsigned* __restrict__ segmax)
{
    const int j = threadIdx.x;
    const float* src = (j < 64) ? k0 : (j < 128) ? k1 : k2;
    const int c = j & 63;
    float s0 = 0.f, s1 = 0.f, m0 = -3.4e38f, m1 = -3.4e38f;
    for (int row = blockIdx.x; row < NPT; row += gridDim.x) {
        float v = src[(size_t)row * CH + c];
        if (bidx[row] == 0) { s0 += v; m0 = fmaxf(m0, v); }
        else                { s1 += v; m1 = fmaxf(m1, v); }
    }
    atomicAdd(&segsum[j], s0);
    atomicAdd(&segsum[CA + j], s1);
    atomicMax(&segmax[j], encf(m0));
    atomicMax(&segmax[CA + j], encf(m1));
}

__global__ __launch_bounds__(384) void att_k(const float* __restrict__ segsum,
    const unsigned* __restrict__ segmax, const int* __restrict__ bidx,
    const float* __restrict__ w1, const float* __restrict__ b1,
    const float* __restrict__ w2, const float* __restrict__ b2,
    const float* __restrict__ ksw, float* __restrict__ att,
    float* __restrict__ wsig)
{
    __shared__ float inl[2][2][CA];   // [path(avg,max)][b][j]
    __shared__ float hid[2][2][HID];
    __shared__ int cnt0s;
    const int t = threadIdx.x;
    if (t == 0) {
        int lo = 0, hi = NPT;  // bidx sorted; find first 1
        while (lo < hi) { int mid = (lo + hi) >> 1; if (bidx[mid] == 0) lo = mid + 1; else hi = mid; }
        cnt0s = lo;
    }
    __syncthreads();
    const float c0 = (float)cnt0s, c1 = (float)(NPT - cnt0s);
    if (t < 2 * CA) {
        int b = t / CA, j = t % CA;
        inl[0][b][j] = segsum[t] / (b ? c1 : c0);
        inl[1][b][j] = decf(segmax[t]);
    }
    __syncthreads();
    if (t < 48) {
        int path = t / 24, b = (t / HID) & 1, h = t % HID;
        float z = b1[h];
        for (int j = 0; j < CA; ++j) z += inl[path][b][j] * w1[j * HID + h];
        hid[path][b][h] = fmaxf(z, 0.f);
    }
    __syncthreads();
    if (t < 2 * CA) {
        int b = t / CA, o = t % CA;
        float za = b2[o], zm = b2[o];
        for (int h = 0; h < HID; ++h) {
            za += hid[0][b][h] * w2[h * CA + o];
            zm += hid[1][b][h] * w2[h * CA + o];
        }
        float z = za + zm;
        att[t] = 1.f / (1.f + expf(-z));
    }
    if (t < 3) wsig[t] = 1.f / (1.f + expf(-ksw[t]));
}

// ---------------------------------------------------------------------------
// Final: out = relu(x + sum_i w[i] * (kx[i] + xcat[:,3c+i]*att[b,3c+i]))
// ---------------------------------------------------------------------------
__global__ __launch_bounds__(256) void final_k(const float* __restrict__ x,
    const float* __restrict__ k0, const float* __restrict__ k1,
    const float* __restrict__ k2, const int* __restrict__ bidx,
    const float* __restrict__ att, const float* __restrict__ wsig,
    float* __restrict__ out)
{
    const float w0 = wsig[0], w1v = wsig[1], w2v = wsig[2];
    for (int i = blockIdx.x * blockDim.x + threadIdx.x; i < NCE;
         i += gridDim.x * blockDim.x) {
        const int n = i >> 6, c = i & 63;
        const int b = bidx[n];
        const float* ab = att + b * CA;
        const size_t nb = (size_t)n * CH;
        float acc = x[i];
        #pragma unroll
        for (int i3 = 0; i3 < 3; ++i3) {
            int j = 3 * c + i3;
            int src = j >> 6, cc = j & 63;
            const float* kp = (src == 0) ? k0 : (src == 1) ? k1 : k2;
            const float* ki = (i3 == 0) ? k0 : (i3 == 1) ? k1 : k2;
            float wv = (i3 == 0) ? w0 : (i3 == 1) ? w1v : w2v;
            acc += wv * (ki[nb + c] + kp[nb + cc] * ab[j]);
        }
        out[i] = fmaxf(acc, 0.f);
    }
}

// ---------------------------------------------------------------------------
extern "C" void kernel_launch(void* const* d_in, const int* in_sizes, int n_in,
                              void* d_out, int out_size, void* d_ws, size_t ws_size,
                              hipStream_t stream)
{
    const float* feats = (const float*)d_in[0];
    const int*   bidx  = (const int*)d_in[1];
    const int*   nbr   = (const int*)d_in[2];
    const float* W1    = (const float*)d_in[3];
    const float* g1    = (const float*)d_in[4];
    const float* b1    = (const float*)d_in[5];
    const float* W2    = (const float*)d_in[6];
    const float* g2    = (const float*)d_in[7];
    const float* b2    = (const float*)d_in[8];
    const float* Wk    = (const float*)d_in[9];
    const float* gk    = (const float*)d_in[10];
    const float* bk    = (const float*)d_in[11];
    const float* fc1w  = (const float*)d_in[12];
    const float* fc1b  = (const float*)d_in[13];
    const float* fc2w  = (const float*)d_in[14];
    const float* fc2b  = (const float*)d_in[15];
    const float* ksw   = (const float*)d_in[16];
    float* out = (float*)d_out;

    // d_out doubles as conv-output scratch A (final_k only writes it at the end)
    float* A  = out;
    float* Bb = (float*)d_ws;
    float* Cc = Bb + NCE;
    float* Dd = Cc + NCE;
    float* small  = Dd + NCE;
    float* bnsum  = small;                 // 5*64
    float* bnss   = bnsum + 5 * 64;        // 5*64
    float* segsum = bnss + 5 * 64;         // 2*192
    unsigned* segmax = (unsigned*)(segsum + 2 * CA);   // 2*192
    float* att  = (float*)(segmax + 2 * CA);           // 2*192
    float* wsig = att + 2 * CA;                        // 3

    hipMemsetAsync(small, 0, (size_t)(5 * 64 * 2 + 2 * CA * 2) * sizeof(float), stream);

    const int GC = NPT / 64;   // 1250
    const size_t WSZ = (size_t)KN * CH * 64;

    // layer 1: relu(bn(conv(x, W1)))
    conv_k<<<GC, 256, 0, stream>>>(feats, nbr, W1, A);
    bnstats_k<<<256, 256, 0, stream>>>(A, bnsum + 0, bnss + 0);
    bnapply_k<true><<<512, 256, 0, stream>>>(A, bnsum + 0, bnss + 0, g1, b1, Bb);
    // layer 2: bn(conv(h, W2)) -- no relu
    conv_k<<<GC, 256, 0, stream>>>(Bb, nbr, W2, A);
    bnstats_k<<<256, 256, 0, stream>>>(A, bnsum + 64, bnss + 64);
    bnapply_k<false><<<512, 256, 0, stream>>>(A, bnsum + 64, bnss + 64, g2, b2, Bb);
    // k-layers
    conv_k<<<GC, 256, 0, stream>>>(Bb, nbr, Wk + 0 * WSZ, A);
    bnstats_k<<<256, 256, 0, stream>>>(A, bnsum + 128, bnss + 128);
    bnapply_k<true><<<512, 256, 0, stream>>>(A, bnsum + 128, bnss + 128, gk + 0, bk + 0, Cc);
    conv_k<<<GC, 256, 0, stream>>>(Cc, nbr, Wk + 1 * WSZ, A);
    bnstats_k<<<256, 256, 0, stream>>>(A, bnsum + 192, bnss + 192);
    bnapply_k<true><<<512, 256, 0, stream>>>(A, bnsum + 192, bnss + 192, gk + 64, bk + 64, Dd);
    conv_k<<<GC, 256, 0, stream>>>(Dd, nbr, Wk + 2 * WSZ, A);
    bnstats_k<<<256, 256, 0, stream>>>(A, bnsum + 256, bnss + 256);
    bnapply_k<true><<<512, 256, 0, stream>>>(A, bnsum + 256, bnss + 256, gk + 128, bk + 128, Bb);
    // channel attention + final blend
    segstat_k<<<256, 192, 0, stream>>>(Cc, Dd, Bb, bidx, segsum, segmax);
    att_k<<<1, 384, 0, stream>>>(segsum, segmax, bidx, fc1w, fc1b, fc2w, fc2b, ksw, att, wsig);
    final_k<<<2048, 256, 0, stream>>>(feats, Cc, Dd, Bb, bidx, att, wsig, out);
}

// Round 3
// 614.297 us; speedup vs baseline: 2.7011x; 2.7011x over previous
//
#include <hip/hip_runtime.h>
#include <hip/hip_bf16.h>
#include <math.h>

#define NPT 80000
#define CH 64
#define KN 27
#define NCE (NPT * CH)      // 5,120,000
#define CA 192
#define HID 12
#define EPSV 1e-5f

typedef __attribute__((ext_vector_type(8))) short short8;   // 8 bf16 (4 VGPRs)
typedef __attribute__((ext_vector_type(4))) float f32x4;

// ---------------------------------------------------------------------------
// fp32 -> bf16 convert (vectorized)
// ---------------------------------------------------------------------------
__global__ __launch_bounds__(256) void tobf_k(const float* __restrict__ in,
                                              __hip_bfloat16* __restrict__ ob)
{
    for (int i = blockIdx.x * blockDim.x + threadIdx.x; i < NCE / 4;
         i += gridDim.x * blockDim.x) {
        float4 v = ((const float4*)in)[i];
        __hip_bfloat16 b4[4] = {__float2bfloat16(v.x), __float2bfloat16(v.y),
                                __float2bfloat16(v.z), __float2bfloat16(v.w)};
        *(uint2*)&ob[(size_t)i * 4] = *(const uint2*)b4;
    }
}

// ---------------------------------------------------------------------------
// Weight prep: fp32 W[tap][ci][co] -> bf16 fragment-ordered Wf[tap][f][lane][e]
// frag f = 2*g + h (g = colgroup 0..3, h = kchunk 0..1); lane l elem e:
//   ci = 32*h + 8*(l>>4) + e, co = 16*g + (l&15)
// ROUND-2 BUG FIX: 256 threads must each pack BOTH g-halves (16 elems), not 8
// -- previously fragments 4..7 (co>=32) were left as ws-poison => half-dead convs.
// ---------------------------------------------------------------------------
__global__ __launch_bounds__(256) void wprep_k(const float* __restrict__ W,
    __hip_bfloat16* __restrict__ Wf, int ntaps)
{
    __shared__ float wl[64][65];
    const int t = threadIdx.x;
    for (int tap = blockIdx.x; tap < ntaps; tap += gridDim.x) {
        const float* Ws = W + (size_t)tap * 4096;
        __syncthreads();
        for (int j = t; j < 4096; j += 256) wl[j >> 6][j & 63] = Ws[j];
        __syncthreads();
        const int f0 = t >> 6, l = t & 63;
        #pragma unroll
        for (int f = f0; f < 8; f += 4) {
            const int g = f >> 1, h = f & 1;
            const int ci0 = 32 * h + 8 * (l >> 4);
            const int co  = 16 * g + (l & 15);
            __hip_bfloat16* dst = Wf + (size_t)tap * 4096 + f * 512 + l * 8;
            #pragma unroll
            for (int e = 0; e < 8; ++e) dst[e] = __float2bfloat16(wl[ci0 + e][co]);
        }
    }
}

// ---------------------------------------------------------------------------
// MFMA sparse conv: block = 64 rows x 64 cols, 4 waves, wave = 16 rows x 64 cols
// ---------------------------------------------------------------------------
#define GLDS(gsrc, ldst) \
    __builtin_amdgcn_global_load_lds((const __attribute__((address_space(1))) void*)(gsrc), \
        (__attribute__((address_space(3))) void*)(ldst), 16, 0, 0)

__global__ __launch_bounds__(256) void conv_mfma(
    const __hip_bfloat16* __restrict__ xb, const int* __restrict__ nbr,
    const __hip_bfloat16* __restrict__ Wf, float* __restrict__ y)
{
    __shared__ short lds_w[2][4096];   // 2 x 8KB double-buffered W tile
    const int t = threadIdx.x;
    const int w = t >> 6, l = t & 63;
    const int l15 = l & 15, l4 = l >> 4;
    const int base = blockIdx.x * 64;
    const size_t rowg = (size_t)base + 16 * w + l15;   // row this lane gathers

    // preload all 27 neighbor indices for this lane's row
    int idxs[KN];
    const int* nrow = nbr + rowg * KN;
    #pragma unroll
    for (int k = 0; k < KN; ++k) idxs[k] = nrow[k];

    f32x4 acc[4] = {};

    // stage tap 0 (wave w stages its 2KB slice via 2x global_load_lds width=16)
    {
        const char* src = (const char*)Wf + (size_t)0 * 8192 + w * 2048 + l * 16;
        char* dst = (char*)&lds_w[0][0] + w * 2048;
        GLDS(src, dst);
        GLDS(src + 1024, dst + 1024);
    }
    __syncthreads();

    #pragma unroll
    for (int tap = 0; tap < KN; ++tap) {
        const int cur = tap & 1;
        if (tap + 1 < KN) {   // async prefetch next tap into other buffer
            const char* src = (const char*)Wf + (size_t)(tap + 1) * 8192 + w * 2048 + l * 16;
            char* dst = (char*)&lds_w[cur ^ 1][0] + w * 2048;
            GLDS(src, dst);
            GLDS(src + 1024, dst + 1024);
        }
        // A fragments: gather 2x16B from this lane's neighbor row
        const int idx = idxs[tap];
        short8 a0 = {}, a1 = {};
        if (idx >= 0) {
            const short* xr = (const short*)xb + (size_t)idx * 64 + l4 * 8;
            a0 = *(const short8*)xr;          // ci 8*l4+e        (chunk 0)
            a1 = *(const short8*)(xr + 32);   // ci 32 + 8*l4+e   (chunk 1)
        }
        // B fragments from LDS (fragment-ordered, contiguous per lane)
        const short* wb = &lds_w[cur][l * 8];
        #pragma unroll
        for (int g = 0; g < 4; ++g) {
            short8 b0 = *(const short8*)(wb + (2 * g) * 512);
            short8 b1 = *(const short8*)(wb + (2 * g + 1) * 512);
            acc[g] = __builtin_amdgcn_mfma_f32_16x16x32_bf16(a0, b0, acc[g], 0, 0, 0);
            acc[g] = __builtin_amdgcn_mfma_f32_16x16x32_bf16(a1, b1, acc[g], 0, 0, 0);
        }
        __syncthreads();   // drains glds prefetch + all waves done reading cur
    }

    // C/D layout: col = 16g + (l&15), row = 4*(l>>4) + j   [m89-verified]
    const int orow = base + 16 * w + l4 * 4;
    #pragma unroll
    for (int g = 0; g < 4; ++g) {
        #pragma unroll
        for (int j = 0; j < 4; ++j)
            y[(size_t)(orow + j) * CH + 16 * g + l15] = acc[g][j];
    }
}

// ---------------------------------------------------------------------------
// BN stats: per-channel sum & sumsq via block partials + atomics
// ---------------------------------------------------------------------------
__global__ __launch_bounds__(256) void bnstats_k(const float* __restrict__ y,
    float* __restrict__ sums, float* __restrict__ ssq)
{
    const int t = threadIdx.x, c = t & 63, rg = t >> 6;
    float s = 0.f, ss = 0.f;
    for (int row = blockIdx.x * 4 + rg; row < NPT; row += gridDim.x * 4) {
        float v = y[(size_t)row * CH + c];
        s += v; ss += v * v;
    }
    __shared__ float ls[4][64], lss[4][64];
    ls[rg][c] = s; lss[rg][c] = ss;
    __syncthreads();
    if (t < 64) {
        float a = ls[0][t] + ls[1][t] + ls[2][t] + ls[3][t];
        float q = lss[0][t] + lss[1][t] + lss[2][t] + lss[3][t];
        atomicAdd(&sums[t], a);
        atomicAdd(&ssq[t], q);
    }
}

// ---------------------------------------------------------------------------
// BN apply (+optional ReLU); writes fp32 and/or bf16 per template
// NOTE: no __restrict on y/o32 — k3 layer runs in-place (elementwise-safe)
// ---------------------------------------------------------------------------
template<bool RELU, bool WF32, bool WBF>
__global__ __launch_bounds__(256) void bnapply_k(const float* y,
    const float* __restrict__ sums, const float* __restrict__ ssq,
    const float* __restrict__ g, const float* __restrict__ b,
    float* o32, __hip_bfloat16* __restrict__ obf)
{
    const float inv = 1.0f / (float)NPT;
    for (int i = blockIdx.x * blockDim.x + threadIdx.x; i < NCE / 4;
         i += gridDim.x * blockDim.x) {
        float4 v = ((const float4*)y)[i];
        const int c0 = (i * 4) & 63;
        float4 r;
        {
            float m = sums[c0+0]*inv; float va = ssq[c0+0]*inv - m*m;
            float sc = rsqrtf(va + EPSV) * g[c0+0];
            r.x = (v.x - m) * sc + b[c0+0];
        }
        {
            float m = sums[c0+1]*inv; float va = ssq[c0+1]*inv - m*m;
            float sc = rsqrtf(va + EPSV) * g[c0+1];
            r.y = (v.y - m) * sc + b[c0+1];
        }
        {
            float m = sums[c0+2]*inv; float va = ssq[c0+2]*inv - m*m;
            float sc = rsqrtf(va + EPSV) * g[c0+2];
            r.z = (v.z - m) * sc + b[c0+2];
        }
        {
            float m = sums[c0+3]*inv; float va = ssq[c0+3]*inv - m*m;
            float sc = rsqrtf(va + EPSV) * g[c0+3];
            r.w = (v.w - m) * sc + b[c0+3];
        }
        if (RELU) {
            r.x = fmaxf(r.x, 0.f); r.y = fmaxf(r.y, 0.f);
            r.z = fmaxf(r.z, 0.f); r.w = fmaxf(r.w, 0.f);
        }
        if (WF32) ((float4*)o32)[i] = r;
        if (WBF) {
            __hip_bfloat16 b4[4] = {__float2bfloat16(r.x), __float2bfloat16(r.y),
                                    __float2bfloat16(r.z), __float2bfloat16(r.w)};
            *(uint2*)&obf[(size_t)i * 4] = *(const uint2*)b4;
        }
    }
}

// ---------------------------------------------------------------------------
// Channel attention: segment sum/max over rows (B=2)
// ---------------------------------------------------------------------------
__device__ __forceinline__ unsigned encf(float f) {
    unsigned u = __float_as_uint(f);
    return (u & 0x80000000u) ? ~u : (u | 0x80000000u);
}
__device__ __forceinline__ float decf(unsigned e) {
    return __uint_as_float((e & 0x80000000u) ? (e & 0x7fffffffu) : ~e);
}

__global__ __launch_bounds__(192) void segstat_k(const float* __restrict__ k0,
    const float* __restrict__ k1, const float* __restrict__ k2,
    const int* __restrict__ bidx, float* __restrict__ segsum,
    unsigned* __restrict__ segmax)
{
    const int j = threadIdx.x;
    const float* src = (j < 64) ? k0 : (j < 128) ? k1 : k2;
    const int c = j & 63;
    float s0 = 0.f, s1 = 0.f, m0 = -3.4e38f, m1 = -3.4e38f;
    for (int row = blockIdx.x; row < NPT; row += gridDim.x) {
        float v = src[(size_t)row * CH + c];
        if (bidx[row] == 0) { s0 += v; m0 = fmaxf(m0, v); }
        else                { s1 += v; m1 = fmaxf(m1, v); }
    }
    atomicAdd(&segsum[j], s0);
    atomicAdd(&segsum[CA + j], s1);
    atomicMax(&segmax[j], encf(m0));
    atomicMax(&segmax[CA + j], encf(m1));
}

__global__ __launch_bounds__(384) void att_k(const float* __restrict__ segsum,
    const unsigned* __restrict__ segmax, const int* __restrict__ bidx,
    const float* __restrict__ w1, const float* __restrict__ b1,
    const float* __restrict__ w2, const float* __restrict__ b2,
    const float* __restrict__ ksw, float* __restrict__ att,
    float* __restrict__ wsig)
{
    __shared__ float inl[2][2][CA];
    __shared__ float hid[2][2][HID];
    __shared__ int cnt0s;
    const int t = threadIdx.x;
    if (t == 0) {
        int lo = 0, hi = NPT;
        while (lo < hi) { int mid = (lo + hi) >> 1; if (bidx[mid] == 0) lo = mid + 1; else hi = mid; }
        cnt0s = lo;
    }
    __syncthreads();
    const float c0 = (float)cnt0s, c1 = (float)(NPT - cnt0s);
    if (t < 2 * CA) {
        int b = t / CA, j = t % CA;
        inl[0][b][j] = segsum[t] / (b ? c1 : c0);
        inl[1][b][j] = decf(segmax[t]);
    }
    __syncthreads();
    if (t < 48) {
        int path = t / 24, b = (t / HID) & 1, h = t % HID;
        float z = b1[h];
        for (int j = 0; j < CA; ++j) z += inl[path][b][j] * w1[j * HID + h];
        hid[path][b][h] = fmaxf(z, 0.f);
    }
    __syncthreads();
    if (t < 2 * CA) {
        int b = t / CA, o = t % CA;
        float za = b2[o], zm = b2[o];
        for (int h = 0; h < HID; ++h) {
            za += hid[0][b][h] * w2[h * CA + o];
            zm += hid[1][b][h] * w2[h * CA + o];
        }
        float z = za + zm;
        att[t] = 1.f / (1.f + expf(-z));
    }
    if (t < 3) wsig[t] = 1.f / (1.f + expf(-ksw[t]));
}

// ---------------------------------------------------------------------------
// Final blend. Block = 4 rows x 64 ch; rows staged in LDS first so running
// with k3 == out (in-place on d_out) is safe.
// ---------------------------------------------------------------------------
__global__ __launch_bounds__(256) void final_k(const float* __restrict__ x,
    const float* __restrict__ k1, const float* __restrict__ k2,
    const float* k3, const int* __restrict__ bidx,
    const float* __restrict__ att, const float* __restrict__ wsig,
    float* out)
{
    __shared__ float s1[4][64], s2[4][64], s3[4][64];
    const int t = threadIdx.x;
    const int r = t >> 6, c = t & 63;
    const float w0 = wsig[0], w1v = wsig[1], w2v = wsig[2];
    for (int n0 = blockIdx.x * 4; n0 < NPT; n0 += gridDim.x * 4) {
        const int n = n0 + r;
        const size_t i = (size_t)n * CH + c;
        __syncthreads();                       // protect LDS reuse across iters
        s1[r][c] = k1[i]; s2[r][c] = k2[i]; s3[r][c] = k3[i];
        __syncthreads();
        const float* ab = att + bidx[n] * CA;
        float acc = x[i];
        const int j0 = 3 * c;
        float kp[3];
        #pragma unroll
        for (int i3 = 0; i3 < 3; ++i3) {
            int j = j0 + i3;
            int s = j >> 6, cc = j & 63;
            const float (*sp)[64] = (s == 0) ? s1 : (s == 1) ? s2 : s3;
            kp[i3] = sp[r][cc] * ab[j];
        }
        acc += w0 * (s1[r][c] + kp[0]) + w1v * (s2[r][c] + kp[1])
             + w2v * (s3[r][c] + kp[2]);
        out[i] = fmaxf(acc, 0.f);
    }
}

// ---------------------------------------------------------------------------
extern "C" void kernel_launch(void* const* d_in, const int* in_sizes, int n_in,
                              void* d_out, int out_size, void* d_ws, size_t ws_size,
                              hipStream_t stream)
{
    const float* feats = (const float*)d_in[0];
    const int*   bidx  = (const int*)d_in[1];
    const int*   nbr   = (const int*)d_in[2];
    const float* W1    = (const float*)d_in[3];
    const float* g1    = (const float*)d_in[4];
    const float* b1    = (const float*)d_in[5];
    const float* W2    = (const float*)d_in[6];
    const float* g2    = (const float*)d_in[7];
    const float* b2    = (const float*)d_in[8];
    const float* Wk    = (const float*)d_in[9];
    const float* gk    = (const float*)d_in[10];
    const float* bk    = (const float*)d_in[11];
    const float* fc1w  = (const float*)d_in[12];
    const float* fc1b  = (const float*)d_in[13];
    const float* fc2w  = (const float*)d_in[14];
    const float* fc2b  = (const float*)d_in[15];
    const float* ksw   = (const float*)d_in[16];
    float* out = (float*)d_out;

    float* A  = out;                     // conv-output scratch lives in d_out
    float* Cc = (float*)d_ws;            // k1 fp32
    float* Dd = Cc + NCE;                // k2 fp32
    __hip_bfloat16* xb = (__hip_bfloat16*)(Dd + NCE);   // rotating bf16 act
    __hip_bfloat16* Wf = xb + NCE;       // 135 taps x 4096 frag-ordered bf16
    float* small = (float*)(Wf + 135 * 4096);
    float* bnsum = small;                          // 5*64
    float* bnss  = bnsum + 5 * 64;                 // 5*64
    float* segsum = bnss + 5 * 64;                 // 2*192
    unsigned* segmax = (unsigned*)(segsum + 2 * CA);  // 2*192
    float* att  = (float*)(segmax + 2 * CA);          // 2*192
    float* wsig = att + 2 * CA;                       // 3

    hipMemsetAsync(small, 0, (size_t)(5 * 64 * 2 + 2 * CA * 2) * sizeof(float), stream);

    const int GC = NPT / 64;   // 1250
    const size_t FT = 27 * 4096;   // Wf elems per layer

    // prep: bf16 feats + fragment-ordered bf16 weights
    tobf_k<<<512, 256, 0, stream>>>(feats, xb);
    wprep_k<<<27, 256, 0, stream>>>(W1, Wf, 27);
    wprep_k<<<27, 256, 0, stream>>>(W2, Wf + FT, 27);
    wprep_k<<<81, 256, 0, stream>>>(Wk, Wf + 2 * FT, 81);

    // layer 1: relu(bn(conv)) -> bf16 only
    conv_mfma<<<GC, 256, 0, stream>>>(xb, nbr, Wf, A);
    bnstats_k<<<256, 256, 0, stream>>>(A, bnsum + 0, bnss + 0);
    bnapply_k<true, false, true><<<512, 256, 0, stream>>>(A, bnsum + 0, bnss + 0, g1, b1, nullptr, xb);
    // layer 2: bn(conv) (no relu) -> bf16 only
    conv_mfma<<<GC, 256, 0, stream>>>(xb, nbr, Wf + FT, A);
    bnstats_k<<<256, 256, 0, stream>>>(A, bnsum + 64, bnss + 64);
    bnapply_k<false, false, true><<<512, 256, 0, stream>>>(A, bnsum + 64, bnss + 64, g2, b2, nullptr, xb);
    // k1 -> fp32 Cc + bf16
    conv_mfma<<<GC, 256, 0, stream>>>(xb, nbr, Wf + 2 * FT, A);
    bnstats_k<<<256, 256, 0, stream>>>(A, bnsum + 128, bnss + 128);
    bnapply_k<true, true, true><<<512, 256, 0, stream>>>(A, bnsum + 128, bnss + 128, gk + 0, bk + 0, Cc, xb);
    // k2 -> fp32 Dd + bf16
    conv_mfma<<<GC, 256, 0, stream>>>(xb, nbr, Wf + 3 * FT, A);
    bnstats_k<<<256, 256, 0, stream>>>(A, bnsum + 192, bnss + 192);
    bnapply_k<true, true, true><<<512, 256, 0, stream>>>(A, bnsum + 192, bnss + 192, gk + 64, bk + 64, Dd, xb);
    // k3 -> fp32 in-place in d_out
    conv_mfma<<<GC, 256, 0, stream>>>(xb, nbr, Wf + 4 * FT, A);
    bnstats_k<<<256, 256, 0, stream>>>(A, bnsum + 256, bnss + 256);
    bnapply_k<true, true, false><<<512, 256, 0, stream>>>(A, bnsum + 256, bnss + 256, gk + 128, bk + 128, A, nullptr);

    // channel attention + final blend (final stages rows -> in-place safe)
    segstat_k<<<256, 192, 0, stream>>>(Cc, Dd, A, bidx, segsum, segmax);
    att_k<<<1, 384, 0, stream>>>(segsum, segmax, bidx, fc1w, fc1b, fc2w, fc2b, ksw, att, wsig);
    final_k<<<2048, 256, 0, stream>>>(feats, Cc, Dd, A, bidx, att, wsig, out);
}

// Round 6
// 547.772 us; speedup vs baseline: 3.0291x; 1.1214x over previous
//
#include <hip/hip_runtime.h>
#include <hip/hip_bf16.h>
#include <math.h>

#define NPT 80000
#define CH 64
#define KN 27
#define NCE (NPT * CH)      // 5,120,000
#define CA 192
#define HID 12
#define EPSV 1e-5f

typedef __attribute__((ext_vector_type(8))) short short8;   // 8 bf16 (4 VGPRs)
typedef __attribute__((ext_vector_type(4))) float f32x4;

__device__ __forceinline__ unsigned encf(float f) {
    unsigned u = __float_as_uint(f);
    return (u & 0x80000000u) ? ~u : (u | 0x80000000u);
}
__device__ __forceinline__ float decf(unsigned e) {
    return __uint_as_float((e & 0x80000000u) ? (e & 0x7fffffffu) : ~e);
}

// ---------------------------------------------------------------------------
// fp32 -> bf16 convert (vectorized)
// ---------------------------------------------------------------------------
__global__ __launch_bounds__(256) void tobf_k(const float* __restrict__ in,
                                              __hip_bfloat16* __restrict__ ob)
{
    for (int i = blockIdx.x * blockDim.x + threadIdx.x; i < NCE / 4;
         i += gridDim.x * blockDim.x) {
        float4 v = ((const float4*)in)[i];
        __hip_bfloat16 b4[4] = {__float2bfloat16(v.x), __float2bfloat16(v.y),
                                __float2bfloat16(v.z), __float2bfloat16(v.w)};
        *(uint2*)&ob[(size_t)i * 4] = *(const uint2*)b4;
    }
}

// ---------------------------------------------------------------------------
// Weight prep: fp32 W[tap][ci][co] -> bf16 fragment-ordered Wf[tap][f][lane][e]
// frag f = 2*g + h; lane l elem e: ci = 32*h + 8*(l>>4) + e, co = 16*g + (l&15)
// ---------------------------------------------------------------------------
__global__ __launch_bounds__(256) void wprep_k(const float* __restrict__ W,
    __hip_bfloat16* __restrict__ Wf, int ntaps)
{
    __shared__ float wl[64][65];
    const int t = threadIdx.x;
    for (int tap = blockIdx.x; tap < ntaps; tap += gridDim.x) {
        const float* Ws = W + (size_t)tap * 4096;
        __syncthreads();
        for (int j = t; j < 4096; j += 256) wl[j >> 6][j & 63] = Ws[j];
        __syncthreads();
        const int f0 = t >> 6, l = t & 63;
        #pragma unroll
        for (int f = f0; f < 8; f += 4) {
            const int g = f >> 1, h = f & 1;
            const int ci0 = 32 * h + 8 * (l >> 4);
            const int co  = 16 * g + (l & 15);
            __hip_bfloat16* dst = Wf + (size_t)tap * 4096 + f * 512 + l * 8;
            #pragma unroll
            for (int e = 0; e < 8; ++e) dst[e] = __float2bfloat16(wl[ci0 + e][co]);
        }
    }
}

// ---------------------------------------------------------------------------
// MFMA sparse conv (round-3-proven form, no fused stats).
// Block = 64 rows x 64 cols, 4 waves, wave = 16 rows x 64 cols.
// ---------------------------------------------------------------------------
#define GLDS(gsrc, ldst) \
    __builtin_amdgcn_global_load_lds((const __attribute__((address_space(1))) void*)(gsrc), \
        (__attribute__((address_space(3))) void*)(ldst), 16, 0, 0)

__global__ __launch_bounds__(256) void conv_mfma(
    const __hip_bfloat16* __restrict__ xb, const int* __restrict__ nbr,
    const __hip_bfloat16* __restrict__ Wf, float* __restrict__ y)
{
    __shared__ short lds_w[2][4096];   // 2 x 8KB double-buffered W tile
    const int t = threadIdx.x;
    const int w = t >> 6, l = t & 63;
    const int l15 = l & 15, l4 = l >> 4;
    const int base = blockIdx.x * 64;
    const size_t rowg = (size_t)base + 16 * w + l15;   // row this lane gathers

    // preload all 27 neighbor indices for this lane's row
    int idxs[KN];
    const int* nrow = nbr + rowg * KN;
    #pragma unroll
    for (int k = 0; k < KN; ++k) idxs[k] = nrow[k];

    f32x4 acc[4] = {};

    // stage tap 0 (wave w stages its 2KB slice via 2x global_load_lds width=16)
    {
        const char* src = (const char*)Wf + (size_t)0 * 8192 + w * 2048 + l * 16;
        char* dst = (char*)&lds_w[0][0] + w * 2048;
        GLDS(src, dst);
        GLDS(src + 1024, dst + 1024);
    }
    __syncthreads();

    #pragma unroll
    for (int tap = 0; tap < KN; ++tap) {
        const int cur = tap & 1;
        if (tap + 1 < KN) {   // async prefetch next tap into other buffer
            const char* src = (const char*)Wf + (size_t)(tap + 1) * 8192 + w * 2048 + l * 16;
            char* dst = (char*)&lds_w[cur ^ 1][0] + w * 2048;
            GLDS(src, dst);
            GLDS(src + 1024, dst + 1024);
        }
        // A fragments: gather 2x16B from this lane's neighbor row
        const int idx = idxs[tap];
        short8 a0 = {}, a1 = {};
        if (idx >= 0) {
            const short* xr = (const short*)xb + (size_t)idx * 64 + l4 * 8;
            a0 = *(const short8*)xr;          // ci 8*l4+e        (chunk 0)
            a1 = *(const short8*)(xr + 32);   // ci 32 + 8*l4+e   (chunk 1)
        }
        // B fragments from LDS (fragment-ordered, contiguous per lane)
        const short* wb = &lds_w[cur][l * 8];
        #pragma unroll
        for (int g = 0; g < 4; ++g) {
            short8 b0 = *(const short8*)(wb + (2 * g) * 512);
            short8 b1 = *(const short8*)(wb + (2 * g + 1) * 512);
            acc[g] = __builtin_amdgcn_mfma_f32_16x16x32_bf16(a0, b0, acc[g], 0, 0, 0);
            acc[g] = __builtin_amdgcn_mfma_f32_16x16x32_bf16(a1, b1, acc[g], 0, 0, 0);
        }
        __syncthreads();   // drains glds prefetch + all waves done reading cur
    }

    // C/D layout: col = 16g + (l&15), row = 4*(l>>4) + j   [m89-verified]
    const int orow = base + 16 * w + l4 * 4;
    #pragma unroll
    for (int g = 0; g < 4; ++g) {
        #pragma unroll
        for (int j = 0; j < 4; ++j)
            y[(size_t)(orow + j) * CH + 16 * g + l15] = acc[g][j];
    }
}

// ---------------------------------------------------------------------------
// BN stats: per-channel sum & sumsq via block partials + atomics (round-3 form)
// ---------------------------------------------------------------------------
__global__ __launch_bounds__(256) void bnstats_k(const float* __restrict__ y,
    float* __restrict__ sums, float* __restrict__ ssq)
{
    const int t = threadIdx.x, c = t & 63, rg = t >> 6;
    float s = 0.f, ss = 0.f;
    for (int row = blockIdx.x * 4 + rg; row < NPT; row += gridDim.x * 4) {
        float v = y[(size_t)row * CH + c];
        s += v; ss += v * v;
    }
    __shared__ float ls[4][64], lss[4][64];
    ls[rg][c] = s; lss[rg][c] = ss;
    __syncthreads();
    if (t < 64) {
        float a = ls[0][t] + ls[1][t] + ls[2][t] + ls[3][t];
        float q = lss[0][t] + lss[1][t] + lss[2][t] + lss[3][t];
        atomicAdd(&sums[t], a);
        atomicAdd(&ssq[t], q);
    }
}

// ---------------------------------------------------------------------------
// BN apply (+optional ReLU); writes fp32 and/or bf16 per template (round-3 form)
// NOTE: no __restrict on y/o32 — k3 layer runs in-place (elementwise-safe)
// ---------------------------------------------------------------------------
template<bool RELU, bool WF32, bool WBF>
__global__ __launch_bounds__(256) void bnapply_k(const float* y,
    const float* __restrict__ sums, const float* __restrict__ ssq,
    const float* __restrict__ g, const float* __restrict__ b,
    float* o32, __hip_bfloat16* __restrict__ obf)
{
    const float inv = 1.0f / (float)NPT;
    for (int i = blockIdx.x * blockDim.x + threadIdx.x; i < NCE / 4;
         i += gridDim.x * blockDim.x) {
        float4 v = ((const float4*)y)[i];
        const int c0 = (i * 4) & 63;
        float4 r;
        {
            float m = sums[c0+0]*inv; float va = ssq[c0+0]*inv - m*m;
            float sc = rsqrtf(va + EPSV) * g[c0+0];
            r.x = (v.x - m) * sc + b[c0+0];
        }
        {
            float m = sums[c0+1]*inv; float va = ssq[c0+1]*inv - m*m;
            float sc = rsqrtf(va + EPSV) * g[c0+1];
            r.y = (v.y - m) * sc + b[c0+1];
        }
        {
            float m = sums[c0+2]*inv; float va = ssq[c0+2]*inv - m*m;
            float sc = rsqrtf(va + EPSV) * g[c0+2];
            r.z = (v.z - m) * sc + b[c0+2];
        }
        {
            float m = sums[c0+3]*inv; float va = ssq[c0+3]*inv - m*m;
            float sc = rsqrtf(va + EPSV) * g[c0+3];
            r.w = (v.w - m) * sc + b[c0+3];
        }
        if (RELU) {
            r.x = fmaxf(r.x, 0.f); r.y = fmaxf(r.y, 0.f);
            r.z = fmaxf(r.z, 0.f); r.w = fmaxf(r.w, 0.f);
        }
        if (WF32) ((float4*)o32)[i] = r;
        if (WBF) {
            __hip_bfloat16 b4[4] = {__float2bfloat16(r.x), __float2bfloat16(r.y),
                                    __float2bfloat16(r.z), __float2bfloat16(r.w)};
            *(uint2*)&obf[(size_t)i * 4] = *(const uint2*)b4;
        }
    }
}

// ---------------------------------------------------------------------------
// Segment sum/max (B=2) — PARALLEL rewrite (round-3 semantics, new internals).
// 768 blocks: block = (source s = b%3, 313-row chunk = b/3). 256 threads =
// 4 row-subgroups x 64 coalesced channels. Predicated batch split, LDS
// reduce, one atomic per (stat,channel) per block.
// Old version: 114 us @ VALUBusy 1.9% (latency-bound). This: ~4x the thread
// count + 4 rows in flight per block.
// ---------------------------------------------------------------------------
__global__ __launch_bounds__(256) void segstat_k(const float* __restrict__ k0,
    const float* __restrict__ k1, const float* __restrict__ k2,
    const int* __restrict__ bidx, float* __restrict__ segsum,
    unsigned* __restrict__ segmax)
{
    const int s = blockIdx.x % 3;
    const int chunk = blockIdx.x / 3;                 // 0..255
    const float* src = (s == 0) ? k0 : (s == 1) ? k1 : k2;
    const int tid = threadIdx.x;
    const int rg = tid >> 6, c = tid & 63;
    const int r0 = chunk * 313;
    const int r1 = (r0 + 313 < NPT) ? r0 + 313 : NPT;
    float s0 = 0.f, s1 = 0.f, m0 = -3.4e38f, m1 = -3.4e38f;
    for (int row = r0 + rg; row < r1; row += 4) {
        float v = src[(size_t)row * CH + c];
        const bool b1v = (bidx[row] != 0);
        s0 += b1v ? 0.f : v;
        s1 += b1v ? v : 0.f;
        m0 = b1v ? m0 : fmaxf(m0, v);
        m1 = b1v ? fmaxf(m1, v) : m1;
    }
    __shared__ float ls0[4][64], ls1[4][64], lm0[4][64], lm1[4][64];
    ls0[rg][c] = s0; ls1[rg][c] = s1; lm0[rg][c] = m0; lm1[rg][c] = m1;
    __syncthreads();
    if (tid < 64) {
        float a0 = ls0[0][tid] + ls0[1][tid] + ls0[2][tid] + ls0[3][tid];
        float a1 = ls1[0][tid] + ls1[1][tid] + ls1[2][tid] + ls1[3][tid];
        float x0 = fmaxf(fmaxf(lm0[0][tid], lm0[1][tid]), fmaxf(lm0[2][tid], lm0[3][tid]));
        float x1 = fmaxf(fmaxf(lm1[0][tid], lm1[1][tid]), fmaxf(lm1[2][tid], lm1[3][tid]));
        const int j = s * 64 + tid;   // xcat channel: source s -> [s*64, s*64+64)
        atomicAdd(&segsum[j], a0);
        atomicAdd(&segsum[CA + j], a1);
        atomicMax(&segmax[j], encf(x0));
        atomicMax(&segmax[CA + j], encf(x1));
    }
}

// ---------------------------------------------------------------------------
// Tiny attention FC (1 block)
// ---------------------------------------------------------------------------
__global__ __launch_bounds__(384) void att_k(const float* __restrict__ segsum,
    const unsigned* __restrict__ segmax, const int* __restrict__ bidx,
    const float* __restrict__ w1, const float* __restrict__ b1,
    const float* __restrict__ w2, const float* __restrict__ b2,
    const float* __restrict__ ksw, float* __restrict__ att,
    float* __restrict__ wsig)
{
    __shared__ float inl[2][2][CA];
    __shared__ float hid[2][2][HID];
    __shared__ int cnt0s;
    const int t = threadIdx.x;
    if (t == 0) {
        int lo = 0, hi = NPT;
        while (lo < hi) { int mid = (lo + hi) >> 1; if (bidx[mid] == 0) lo = mid + 1; else hi = mid; }
        cnt0s = lo;
    }
    __syncthreads();
    const float c0 = (float)cnt0s, c1 = (float)(NPT - cnt0s);
    if (t < 2 * CA) {
        int b = t / CA, j = t % CA;
        inl[0][b][j] = segsum[t] / (b ? c1 : c0);
        inl[1][b][j] = decf(segmax[t]);
    }
    __syncthreads();
    if (t < 48) {
        int path = t / 24, b = (t / HID) & 1, h = t % HID;
        float z = b1[h];
        for (int j = 0; j < CA; ++j) z += inl[path][b][j] * w1[j * HID + h];
        hid[path][b][h] = fmaxf(z, 0.f);
    }
    __syncthreads();
    if (t < 2 * CA) {
        int b = t / CA, o = t % CA;
        float za = b2[o], zm = b2[o];
        for (int h = 0; h < HID; ++h) {
            za += hid[0][b][h] * w2[h * CA + o];
            zm += hid[1][b][h] * w2[h * CA + o];
        }
        float z = za + zm;
        att[t] = 1.f / (1.f + expf(-z));
    }
    if (t < 3) wsig[t] = 1.f / (1.f + expf(-ksw[t]));
}

// ---------------------------------------------------------------------------
// Final blend. Block = 4 rows x 64 ch; rows staged in LDS first so running
// with k3 == out (in-place on d_out) is safe.
// ---------------------------------------------------------------------------
__global__ __launch_bounds__(256) void final_k(const float* __restrict__ x,
    const float* __restrict__ k1, const float* __restrict__ k2,
    const float* k3, const int* __restrict__ bidx,
    const float* __restrict__ att, const float* __restrict__ wsig,
    float* out)
{
    __shared__ float s1[4][64], s2[4][64], s3[4][64];
    const int t = threadIdx.x;
    const int r = t >> 6, c = t & 63;
    const float w0 = wsig[0], w1v = wsig[1], w2v = wsig[2];
    for (int n0 = blockIdx.x * 4; n0 < NPT; n0 += gridDim.x * 4) {
        const int n = n0 + r;
        const size_t i = (size_t)n * CH + c;
        __syncthreads();                       // protect LDS reuse across iters
        s1[r][c] = k1[i]; s2[r][c] = k2[i]; s3[r][c] = k3[i];
        __syncthreads();
        const float* ab = att + bidx[n] * CA;
        float acc = x[i];
        const int j0 = 3 * c;
        float kp[3];
        #pragma unroll
        for (int i3 = 0; i3 < 3; ++i3) {
            int j = j0 + i3;
            int s = j >> 6, cc = j & 63;
            const float (*sp)[64] = (s == 0) ? s1 : (s == 1) ? s2 : s3;
            kp[i3] = sp[r][cc] * ab[j];
        }
        acc += w0 * (s1[r][c] + kp[0]) + w1v * (s2[r][c] + kp[1])
             + w2v * (s3[r][c] + kp[2]);
        out[i] = fmaxf(acc, 0.f);
    }
}

// ---------------------------------------------------------------------------
extern "C" void kernel_launch(void* const* d_in, const int* in_sizes, int n_in,
                              void* d_out, int out_size, void* d_ws, size_t ws_size,
                              hipStream_t stream)
{
    const float* feats = (const float*)d_in[0];
    const int*   bidx  = (const int*)d_in[1];
    const int*   nbr   = (const int*)d_in[2];
    const float* W1    = (const float*)d_in[3];
    const float* g1    = (const float*)d_in[4];
    const float* b1    = (const float*)d_in[5];
    const float* W2    = (const float*)d_in[6];
    const float* g2    = (const float*)d_in[7];
    const float* b2    = (const float*)d_in[8];
    const float* Wk    = (const float*)d_in[9];
    const float* gk    = (const float*)d_in[10];
    const float* bk    = (const float*)d_in[11];
    const float* fc1w  = (const float*)d_in[12];
    const float* fc1b  = (const float*)d_in[13];
    const float* fc2w  = (const float*)d_in[14];
    const float* fc2b  = (const float*)d_in[15];
    const float* ksw   = (const float*)d_in[16];
    float* out = (float*)d_out;

    float* A  = out;                     // conv-output scratch lives in d_out
    float* Cc = (float*)d_ws;            // k1 fp32
    float* Dd = Cc + NCE;                // k2 fp32
    __hip_bfloat16* xb = (__hip_bfloat16*)(Dd + NCE);   // rotating bf16 act
    __hip_bfloat16* Wf = xb + NCE;       // 135 taps x 4096 frag-ordered bf16
    float* small = (float*)(Wf + 135 * 4096);
    float* bnsum = small;                          // 5*64
    float* bnss  = bnsum + 5 * 64;                 // 5*64
    float* segsum = bnss + 5 * 64;                 // 2*192
    unsigned* segmax = (unsigned*)(segsum + 2 * CA);  // 2*192
    float* att  = (float*)(segmax + 2 * CA);          // 2*192
    float* wsig = att + 2 * CA;                       // 3

    hipMemsetAsync(small, 0, (size_t)(5 * 64 * 2 + 2 * CA * 2) * sizeof(float), stream);

    const int GC = NPT / 64;   // 1250
    const size_t FT = 27 * 4096;   // Wf elems per layer

    // prep: bf16 feats + fragment-ordered bf16 weights
    tobf_k<<<512, 256, 0, stream>>>(feats, xb);
    wprep_k<<<27, 256, 0, stream>>>(W1, Wf, 27);
    wprep_k<<<27, 256, 0, stream>>>(W2, Wf + FT, 27);
    wprep_k<<<81, 256, 0, stream>>>(Wk, Wf + 2 * FT, 81);

    // layer 1: relu(bn(conv)) -> bf16 only
    conv_mfma<<<GC, 256, 0, stream>>>(xb, nbr, Wf, A);
    bnstats_k<<<256, 256, 0, stream>>>(A, bnsum + 0, bnss + 0);
    bnapply_k<true, false, true><<<512, 256, 0, stream>>>(A, bnsum + 0, bnss + 0, g1, b1, nullptr, xb);
    // layer 2: bn(conv) (no relu) -> bf16 only
    conv_mfma<<<GC, 256, 0, stream>>>(xb, nbr, Wf + FT, A);
    bnstats_k<<<256, 256, 0, stream>>>(A, bnsum + 64, bnss + 64);
    bnapply_k<false, false, true><<<512, 256, 0, stream>>>(A, bnsum + 64, bnss + 64, g2, b2, nullptr, xb);
    // k1 -> fp32 Cc + bf16
    conv_mfma<<<GC, 256, 0, stream>>>(xb, nbr, Wf + 2 * FT, A);
    bnstats_k<<<256, 256, 0, stream>>>(A, bnsum + 128, bnss + 128);
    bnapply_k<true, true, true><<<512, 256, 0, stream>>>(A, bnsum + 128, bnss + 128, gk + 0, bk + 0, Cc, xb);
    // k2 -> fp32 Dd + bf16
    conv_mfma<<<GC, 256, 0, stream>>>(xb, nbr, Wf + 3 * FT, A);
    bnstats_k<<<256, 256, 0, stream>>>(A, bnsum + 192, bnss + 192);
    bnapply_k<true, true, true><<<512, 256, 0, stream>>>(A, bnsum + 192, bnss + 192, gk + 64, bk + 64, Dd, xb);
    // k3 -> fp32 in-place in d_out
    conv_mfma<<<GC, 256, 0, stream>>>(xb, nbr, Wf + 4 * FT, A);
    bnstats_k<<<256, 256, 0, stream>>>(A, bnsum + 256, bnss + 256);
    bnapply_k<true, true, false><<<512, 256, 0, stream>>>(A, bnsum + 256, bnss + 256, gk + 128, bk + 128, A, nullptr);

    // channel attention + final blend (final stages rows -> in-place safe)
    segstat_k<<<768, 256, 0, stream>>>(Cc, Dd, A, bidx, segsum, segmax);
    att_k<<<1, 384, 0, stream>>>(segsum, segmax, bidx, fc1w, fc1b, fc2w, fc2b, ksw, att, wsig);
    final_k<<<2048, 256, 0, stream>>>(feats, Cc, Dd, A, bidx, att, wsig, out);
}